// Round 1
// baseline (1662.466 us; speedup 1.0000x reference)
//
#include <hip/hip_runtime.h>
#include <stdint.h>

// Problem constants (from reference)
#define B_   32
#define T_   63      // S-1
#define U_   512
#define E_   256
#define V_   32000
#define L_   64
#define FU_  2048    // 4U
#define KFC_ 1024    // 2U
#define MROW_ 2016   // B*T

typedef float f32x4 __attribute__((ext_vector_type(4)));
typedef __bf16 bf16x8 __attribute__((ext_vector_type(8)));

__device__ __forceinline__ unsigned short f2bf(float f) {
  union { float f; unsigned u; } v; v.f = f;
  unsigned u = v.u;
  u += 0x7FFFu + ((u >> 16) & 1u);   // round-to-nearest-even
  return (unsigned short)(u >> 16);
}
__device__ __forceinline__ float bf2f(unsigned short h) {
  union { unsigned u; float f; } v; v.u = ((unsigned)h) << 16;
  return v.f;
}

// ---------------------------------------------------------------- k_zero
__global__ __launch_bounds__(256) void k_zero(unsigned int* ctr, float* row_sums) {
  int i = blockIdx.x * 256 + threadIdx.x;
  if (i == 0) *ctr = 0u;
  if (i < MROW_) row_sums[i] = 0.f;
}

// ---------------------------------------------------------------- k_fragWh
// fragWh[ct][kc][lane][j] = bf16(W_h[kc*32 + (lane>>4)*8 + j][ct*16 + (lane&15)])
__global__ __launch_bounds__(256) void k_fragWh(const float* __restrict__ W_h,
                                                unsigned short* __restrict__ fragWh) {
  int idx = blockIdx.x * 256 + threadIdx.x;   // 0..131071 = 128ct * 16kc * 64lane
  int lane = idx & 63;
  int kc   = (idx >> 6) & 15;
  int ct   = idx >> 10;
  int quad = lane >> 4, l15 = lane & 15;
  int col = ct * 16 + l15;
  unsigned short* dst = fragWh + (size_t)idx * 8;
#pragma unroll
  for (int j = 0; j < 8; ++j) {
    int k = kc * 32 + quad * 8 + j;
    dst[j] = f2bf(W_h[(size_t)k * FU_ + col]);
  }
}

// ---------------------------------------------------------------- k_zx
// Zx[t][b][col] = emb[target[b,t]] @ W_x + b_lstm
__global__ __launch_bounds__(256) void k_zx(const int* __restrict__ target,
    const float* __restrict__ emb, const float* __restrict__ W_x,
    const float* __restrict__ b_lstm, float* __restrict__ Zx) {
  __shared__ float x_lds[B_ * E_];   // 32 KB
  int t  = blockIdx.x;    // 0..62
  int cc = blockIdx.y;    // 0..7
  int tid = threadIdx.x;
  for (int i = tid; i < B_ * E_; i += 256) {
    int b = i >> 8, e = i & 255;
    x_lds[i] = emb[(size_t)target[b * 64 + t] * E_ + e];
  }
  __syncthreads();
  int col = cc * 256 + tid;
  float acc[B_];
#pragma unroll
  for (int b = 0; b < B_; ++b) acc[b] = 0.f;
  for (int e4 = 0; e4 < E_ / 4; ++e4) {
    float w0 = W_x[(size_t)(4 * e4 + 0) * FU_ + col];
    float w1 = W_x[(size_t)(4 * e4 + 1) * FU_ + col];
    float w2 = W_x[(size_t)(4 * e4 + 2) * FU_ + col];
    float w3 = W_x[(size_t)(4 * e4 + 3) * FU_ + col];
#pragma unroll
    for (int b = 0; b < B_; ++b) {
      f32x4 xv = *(const f32x4*)&x_lds[b * E_ + 4 * e4];
      acc[b] += xv[0] * w0 + xv[1] * w1 + xv[2] * w2 + xv[3] * w3;
    }
  }
  float bias = b_lstm[col];
#pragma unroll
  for (int b = 0; b < B_; ++b)
    Zx[((size_t)(t * B_ + b)) * FU_ + col] = acc[b] + bias;
}

// ---------------------------------------------------------------- k_encproj
// enc_proj[b,l,v] = sum_u enc[b,l,u] * Wa[u,v]
__global__ __launch_bounds__(256) void k_encproj(const float* __restrict__ enc_out,
    const float* __restrict__ Wa, float* __restrict__ enc_proj) {
  __shared__ float e_lds[16 * U_];   // 32 KB
  int rc = blockIdx.x;   // 0..127 (16 rows each)
  int cc = blockIdx.y;   // 0..1
  int tid = threadIdx.x;
  int row0 = rc * 16;
  for (int i = tid; i < 16 * U_; i += 256)
    e_lds[i] = enc_out[(size_t)(row0 + (i >> 9)) * U_ + (i & 511)];
  __syncthreads();
  int col = cc * 256 + tid;
  float acc[16];
#pragma unroll
  for (int r = 0; r < 16; ++r) acc[r] = 0.f;
  for (int k4 = 0; k4 < U_ / 4; ++k4) {
    float w0 = Wa[(size_t)(4 * k4 + 0) * U_ + col];
    float w1 = Wa[(size_t)(4 * k4 + 1) * U_ + col];
    float w2 = Wa[(size_t)(4 * k4 + 2) * U_ + col];
    float w3 = Wa[(size_t)(4 * k4 + 3) * U_ + col];
#pragma unroll
    for (int r = 0; r < 16; ++r) {
      f32x4 xv = *(const f32x4*)&e_lds[r * U_ + 4 * k4];
      acc[r] += xv[0] * w0 + xv[1] * w1 + xv[2] * w2 + xv[3] * w3;
    }
  }
#pragma unroll
  for (int r = 0; r < 16; ++r)
    enc_proj[(size_t)(row0 + r) * U_ + col] = acc[r];
}

// ---------------------------------------------------------------- k_wfcT
// WfcT[n][k] = bf16(W_fc[k][n])
__global__ __launch_bounds__(256) void k_wfcT(const float* __restrict__ W_fc,
                                              unsigned short* __restrict__ WfcT) {
  __shared__ float tile[32][33];
  int nb = blockIdx.x;   // 0..999
  int kb = blockIdx.y;   // 0..31
  int tid = threadIdx.x;
  int r = tid >> 5, c = tid & 31;
#pragma unroll
  for (int i = 0; i < 4; ++i)
    tile[r + 8 * i][c] = W_fc[(size_t)(kb * 32 + r + 8 * i) * V_ + nb * 32 + c];
  __syncthreads();
#pragma unroll
  for (int i = 0; i < 4; ++i)
    WfcT[(size_t)(nb * 32 + r + 8 * i) * KFC_ + kb * 32 + c] = f2bf(tile[c][r + 8 * i]);
}

// ---------------------------------------------------------------- grid barrier
// Monotone-target arrival counter; 32 blocks guaranteed co-resident on 256 CUs.
__device__ __forceinline__ void grid_barrier(unsigned int* ctr, unsigned target) {
  __syncthreads();
  if (threadIdx.x == 0) {
    __threadfence();                      // release: flush our writes device-wide
    atomicAdd(ctr, 1u);
    while (atomicAdd(ctr, 0u) < target) __builtin_amdgcn_s_sleep(2);
    __threadfence();                      // acquire: invalidate stale cached lines
  }
  __syncthreads();
}

// ---------------------------------------------------------------- k_rec
// 32 blocks x 256 threads. Block g owns u-slice [g*16, g*16+16) and batch b=g for attention.
__global__ __launch_bounds__(256) void k_rec(const float* __restrict__ enc_out,
    const float* __restrict__ enc_h0, const float* __restrict__ enc_c0,
    const float* __restrict__ enc_proj, const float* __restrict__ Zx,
    const unsigned short* __restrict__ fragWh,
    unsigned short* hglob,                 // 2 buffers of B_*U_ bf16
    unsigned short* __restrict__ Afc,      // 2048 x 1024 bf16 [ctx | h]
    unsigned int* ctr) {
  __shared__ unsigned short h_lds[B_ * 520];   // padded rows: 1040B = 65*16B, 2-way banks
  __shared__ float z_lds[B_ * 64];
  __shared__ float c_lds[B_ * 16];
  __shared__ float h_sh[U_];
  __shared__ float sc_part[4 * L_];
  __shared__ float probs[L_];

  const int tid = threadIdx.x;
  const int g = blockIdx.x;
  const int w = tid >> 6;
  const int lane = tid & 63;
  const int quad = lane >> 4;
  const int l15 = lane & 15;

  // init: c slice into LDS (fp32, persistent), h0 -> hglob[0] (bf16)
  for (int p = tid; p < 512; p += 256) {
    int b = p >> 4, up = p & 15;
    c_lds[b * 16 + up] = enc_c0[(size_t)b * U_ + g * 16 + up];
    hglob[(size_t)b * U_ + g * 16 + up] = f2bf(enc_h0[(size_t)b * U_ + g * 16 + up]);
  }
  unsigned bar = 0;
  grid_barrier(ctr, ++bar * gridDim.x);

  int cur = 0;
  for (int t = 0; t < T_; ++t) {
    const unsigned short* hsrc = hglob + (size_t)cur * (B_ * U_);
    unsigned short* hdst = hglob + (size_t)(cur ^ 1) * (B_ * U_);

    // stage h (bf16 32x512) -> LDS padded
    for (int c = tid; c < (B_ * U_) / 8; c += 256) {
      int b = c >> 6, u0 = (c & 63) * 8;
      f32x4 v = *(const f32x4*)(hsrc + (size_t)b * U_ + u0);
      *(f32x4*)&h_lds[b * 520 + u0] = v;
    }
    __syncthreads();

    // z-slice = h @ W_h  (wave w handles gate w: cols w*512 + g*16 + [0,16))
    f32x4 acc0 = {0.f, 0.f, 0.f, 0.f}, acc1 = {0.f, 0.f, 0.f, 0.f};
    const unsigned short* bbase = fragWh + ((size_t)(w * 32 + g) * 16) * 64 * 8;
#pragma unroll
    for (int kc = 0; kc < 16; ++kc) {
      bf16x8 bf = *(const bf16x8*)(bbase + (size_t)(kc * 64 + lane) * 8);
      bf16x8 a0 = *(const bf16x8*)&h_lds[l15 * 520 + kc * 32 + quad * 8];
      bf16x8 a1 = *(const bf16x8*)&h_lds[(16 + l15) * 520 + kc * 32 + quad * 8];
      acc0 = __builtin_amdgcn_mfma_f32_16x16x32_bf16(a0, bf, acc0, 0, 0, 0);
      acc1 = __builtin_amdgcn_mfma_f32_16x16x32_bf16(a1, bf, acc1, 0, 0, 0);
    }
#pragma unroll
    for (int r = 0; r < 4; ++r) {
      z_lds[(quad * 4 + r) * 64 + w * 16 + l15] = acc0[r];
      z_lds[(16 + quad * 4 + r) * 64 + w * 16 + l15] = acc1[r];
    }
    __syncthreads();

    // gates + state update (c fp32-resident), write h bf16 (global + Afc h-half)
    for (int p = tid; p < 512; p += 256) {
      int b = p >> 4, up = p & 15;
      const float* zx = Zx + ((size_t)(t * B_ + b)) * FU_ + g * 16 + up;
      float zi = z_lds[b * 64 + 0 * 16 + up] + zx[0 * U_];
      float zf = z_lds[b * 64 + 1 * 16 + up] + zx[1 * U_];
      float zg = z_lds[b * 64 + 2 * 16 + up] + zx[2 * U_];
      float zo = z_lds[b * 64 + 3 * 16 + up] + zx[3 * U_];
      float ii = 1.f / (1.f + expf(-zi));
      float ff = 1.f / (1.f + expf(-zf));
      float gg = tanhf(zg);
      float oo = 1.f / (1.f + expf(-zo));
      float c = ff * c_lds[b * 16 + up] + ii * gg;
      c_lds[b * 16 + up] = c;
      float h = oo * tanhf(c);
      unsigned short hb = f2bf(h);
      hdst[(size_t)b * U_ + g * 16 + up] = hb;
      Afc[(size_t)(t * B_ + b) * KFC_ + U_ + g * 16 + up] = hb;
    }
    grid_barrier(ctr, ++bar * gridDim.x);   // h[t] complete everywhere

    // attention for batch b = g
    {
      const int b = g;
      for (int u = tid; u < U_; u += 256) h_sh[u] = bf2f(hdst[(size_t)b * U_ + u]);
      __syncthreads();
      {
        int l = tid & 63, part = tid >> 6;
        const float* ep = enc_proj + ((size_t)(b * L_ + l)) * U_ + part * 128;
        const float* hs = h_sh + part * 128;
        float s = 0.f;
#pragma unroll 8
        for (int u = 0; u < 128; u += 4) {
          f32x4 e = *(const f32x4*)(ep + u);
          s += hs[u] * e[0] + hs[u + 1] * e[1] + hs[u + 2] * e[2] + hs[u + 3] * e[3];
        }
        sc_part[part * L_ + l] = s;
      }
      __syncthreads();
      if (tid < 64) {
        float s = sc_part[tid] + sc_part[64 + tid] + sc_part[128 + tid] + sc_part[192 + tid];
        float m = s;
#pragma unroll
        for (int off = 32; off >= 1; off >>= 1) m = fmaxf(m, __shfl_xor(m, off));
        float e = expf(s - m);
        float sum = e;
#pragma unroll
        for (int off = 32; off >= 1; off >>= 1) sum += __shfl_xor(sum, off);
        probs[tid] = e / sum;
      }
      __syncthreads();
      for (int u = tid; u < U_; u += 256) {
        float c = 0.f;
        const float* eo = enc_out + ((size_t)b * L_) * U_ + u;
#pragma unroll 16
        for (int l = 0; l < L_; ++l) c += probs[l] * eo[(size_t)l * U_];
        Afc[(size_t)(t * B_ + b) * KFC_ + u] = f2bf(c);
      }
    }
    __syncthreads();
    cur ^= 1;
  }
}

// ---------------------------------------------------------------- k_fc
// (2016x1024) @ (1024x32000) bf16 MFMA, fused tanh(+bias) + per-row sum(exp) atomics.
// 128x128 tile, BK=32, XOR-swizzled LDS segs -> 2-way (free) bank aliasing on b128 reads.
__global__ __launch_bounds__(256) void k_fc(const unsigned short* __restrict__ Afc,
    const unsigned short* __restrict__ WfcT, const float* __restrict__ b_fc,
    float* __restrict__ out, float* __restrict__ row_sums) {
  __shared__ unsigned short At[128 * 32];
  __shared__ unsigned short Bt[128 * 32];
  __shared__ float rs[128];
  const int tid = threadIdx.x;
  const int w = tid >> 6, lane = tid & 63, quad = lane >> 4, l15 = lane & 15;
  const int row0 = blockIdx.y * 128, col0 = blockIdx.x * 128;
  const int mh = (w >> 1) * 64, nh = (w & 1) * 64;

  f32x4 acc[4][4];
#pragma unroll
  for (int i = 0; i < 4; ++i)
#pragma unroll
    for (int j = 0; j < 4; ++j) { f32x4 z = {0.f, 0.f, 0.f, 0.f}; acc[i][j] = z; }

  for (int kt = 0; kt < KFC_ / 32; ++kt) {
    int k0 = kt * 32;
#pragma unroll
    for (int i = 0; i < 2; ++i) {
      int lin = i * 256 + tid;
      int r = lin >> 2, s = lin & 3;
      int gseg = (s - (r >> 1)) & 3;     // XOR swizzle: slot s holds k-seg gseg
      f32x4 va = *(const f32x4*)(Afc + ((size_t)(row0 + r)) * KFC_ + k0 + gseg * 8);
      *(f32x4*)&At[r * 32 + s * 8] = va;
      f32x4 vb = *(const f32x4*)(WfcT + ((size_t)(col0 + r)) * KFC_ + k0 + gseg * 8);
      *(f32x4*)&Bt[r * 32 + s * 8] = vb;
    }
    __syncthreads();
    bf16x8 a[4], b[4];
#pragma unroll
    for (int i = 0; i < 4; ++i) {
      int m = mh + i * 16 + l15;
      a[i] = *(const bf16x8*)&At[m * 32 + (((quad + (m >> 1)) & 3) * 8)];
      int n = nh + i * 16 + l15;
      b[i] = *(const bf16x8*)&Bt[n * 32 + (((quad + (n >> 1)) & 3) * 8)];
    }
#pragma unroll
    for (int i = 0; i < 4; ++i)
#pragma unroll
      for (int j = 0; j < 4; ++j)
        acc[i][j] = __builtin_amdgcn_mfma_f32_16x16x32_bf16(a[i], b[j], acc[i][j], 0, 0, 0);
    __syncthreads();
  }

  // epilogue: tanh(+bias), store to out[b][t][v], accumulate row sum(exp)
  if (tid < 128) rs[tid] = 0.f;
  __syncthreads();
  float bv[4];
#pragma unroll
  for (int j = 0; j < 4; ++j) bv[j] = b_fc[col0 + nh + j * 16 + l15];
  float rp[4][4];
#pragma unroll
  for (int i = 0; i < 4; ++i)
#pragma unroll
    for (int r = 0; r < 4; ++r) rp[i][r] = 0.f;
#pragma unroll
  for (int i = 0; i < 4; ++i) {
#pragma unroll
    for (int j = 0; j < 4; ++j) {
      int cg = col0 + nh + j * 16 + l15;
#pragma unroll
      for (int r = 0; r < 4; ++r) {
        float val = tanhf(acc[i][j][r] + bv[j]);
        int rg = row0 + mh + i * 16 + quad * 4 + r;
        if (rg < MROW_) {
          int b = rg & 31, t = rg >> 5;
          out[((size_t)(b * T_ + t)) * V_ + cg] = val;
        }
        rp[i][r] += expf(val);
      }
    }
  }
#pragma unroll
  for (int i = 0; i < 4; ++i)
#pragma unroll
    for (int r = 0; r < 4; ++r) {
      float v = rp[i][r];
      v += __shfl_xor(v, 1); v += __shfl_xor(v, 2);
      v += __shfl_xor(v, 4); v += __shfl_xor(v, 8);
      if (l15 == 0) atomicAdd(&rs[mh + i * 16 + quad * 4 + r], v);
    }
  __syncthreads();
  if (tid < 128) {
    int rg = row0 + tid;
    if (rg < MROW_) atomicAdd(&row_sums[rg], rs[tid]);
  }
}

// ---------------------------------------------------------------- k_lsm
// out -= log(row_sum)   (tanh bounds logits so no max shift needed)
__global__ __launch_bounds__(256) void k_lsm(float* __restrict__ out,
                                             const float* __restrict__ row_sums, int n4) {
  int i = blockIdx.x * 256 + threadIdx.x;
  if (i >= n4) return;
  f32x4* o4 = (f32x4*)out;
  f32x4 v = o4[i];
  int r = i / 8000;              // V/4 = 8000 vec4 per row; row = b*63 + t
  int b = r / 63, t = r - b * 63;
  float ls = logf(row_sums[t * 32 + b]);
  v[0] -= ls; v[1] -= ls; v[2] -= ls; v[3] -= ls;
  o4[i] = v;
}

// ---------------------------------------------------------------- launch
extern "C" void kernel_launch(void* const* d_in, const int* in_sizes, int n_in,
                              void* d_out, int out_size, void* d_ws, size_t ws_size,
                              hipStream_t stream) {
  const int*   target  = (const int*)d_in[0];
  const float* enc_out = (const float*)d_in[1];
  const float* enc_h0  = (const float*)d_in[2];
  const float* enc_c0  = (const float*)d_in[3];
  const float* emb     = (const float*)d_in[4];
  const float* W_x     = (const float*)d_in[5];
  const float* W_h     = (const float*)d_in[6];
  const float* b_lstm  = (const float*)d_in[7];
  const float* Wa      = (const float*)d_in[8];
  const float* W_fc    = (const float*)d_in[9];
  const float* b_fc    = (const float*)d_in[10];
  float* out = (float*)d_out;
  char* ws = (char*)d_ws;

  // ws layout (bytes); total ~88.3 MiB
  unsigned int*   ctr      = (unsigned int*)(ws + 0);
  float*          row_sums = (float*)(ws + 1024);                 // 2016 f32
  unsigned short* fragWh   = (unsigned short*)(ws + 16384);       // 2 MiB
  unsigned short* hglob    = (unsigned short*)(ws + 2113536);     // 64 KiB (2 bufs)
  float*          Zx       = (float*)(ws + 2179072);              // 16.5 MB
  float*          enc_proj = (float*)(ws + 18694144);             // 4 MiB
  unsigned short* Afc      = (unsigned short*)(ws + 22888448);    // 4 MiB (2048x1024)
  unsigned short* WfcT     = (unsigned short*)(ws + 27082752);    // 62.5 MiB

  k_zero   <<<dim3(8),          dim3(256), 0, stream>>>(ctr, row_sums);
  k_fragWh <<<dim3(512),        dim3(256), 0, stream>>>(W_h, fragWh);
  k_zx     <<<dim3(63, 8),      dim3(256), 0, stream>>>(target, emb, W_x, b_lstm, Zx);
  k_encproj<<<dim3(128, 2),     dim3(256), 0, stream>>>(enc_out, Wa, enc_proj);
  k_wfcT   <<<dim3(1000, 32),   dim3(256), 0, stream>>>(W_fc, WfcT);
  k_rec    <<<dim3(32),         dim3(256), 0, stream>>>(enc_out, enc_h0, enc_c0,
                                                        enc_proj, Zx, fragWh, hglob, Afc, ctr);
  k_fc     <<<dim3(250, 16),    dim3(256), 0, stream>>>(Afc, WfcT, b_fc, out, row_sums);
  k_lsm    <<<dim3(63000),      dim3(256), 0, stream>>>(out, row_sums, 16128000);
}

// Round 2
// 1373.760 us; speedup vs baseline: 1.2102x; 1.2102x over previous
//
#include <hip/hip_runtime.h>
#include <stdint.h>

// Problem constants (from reference)
#define B_   32
#define T_   63      // S-1
#define U_   512
#define E_   256
#define V_   32000
#define L_   64
#define FU_  2048    // 4U
#define KFC_ 1024    // 2U
#define MROW_ 2016   // B*T

typedef float f32x4 __attribute__((ext_vector_type(4)));
typedef float f32x2 __attribute__((ext_vector_type(2)));
typedef __bf16 bf16x8 __attribute__((ext_vector_type(8)));

__device__ __forceinline__ unsigned short f2bf(float f) {
  union { float f; unsigned u; } v; v.f = f;
  unsigned u = v.u;
  u += 0x7FFFu + ((u >> 16) & 1u);   // round-to-nearest-even
  return (unsigned short)(u >> 16);
}
__device__ __forceinline__ float bf2f(unsigned short h) {
  union { unsigned u; float f; } v; v.u = ((unsigned)h) << 16;
  return v.f;
}

// ---------------------------------------------------------------- k_zero
__global__ __launch_bounds__(256) void k_zero(unsigned int* hcnt, float* row_sums) {
  int i = blockIdx.x * 256 + threadIdx.x;
  if (i < 64) hcnt[i] = 0u;
  if (i < MROW_) row_sums[i] = 0.f;
}

// ---------------------------------------------------------------- k_fragWh
// fragWh[ct][kc][lane][j] = bf16(W_h[kc*32 + (lane>>4)*8 + j][ct*16 + (lane&15)])
__global__ __launch_bounds__(256) void k_fragWh(const float* __restrict__ W_h,
                                                unsigned short* __restrict__ fragWh) {
  int idx = blockIdx.x * 256 + threadIdx.x;   // 0..131071 = 128ct * 16kc * 64lane
  int lane = idx & 63;
  int kc   = (idx >> 6) & 15;
  int ct   = idx >> 10;
  int quad = lane >> 4, l15 = lane & 15;
  int col = ct * 16 + l15;
  unsigned short* dst = fragWh + (size_t)idx * 8;
#pragma unroll
  for (int j = 0; j < 8; ++j) {
    int k = kc * 32 + quad * 8 + j;
    dst[j] = f2bf(W_h[(size_t)k * FU_ + col]);
  }
}

// ---------------------------------------------------------------- k_zx
// Zx[t][b][col] = emb[target[b,t]] @ W_x + b_lstm
__global__ __launch_bounds__(256) void k_zx(const int* __restrict__ target,
    const float* __restrict__ emb, const float* __restrict__ W_x,
    const float* __restrict__ b_lstm, float* __restrict__ Zx) {
  __shared__ float x_lds[B_ * E_];   // 32 KB
  int t  = blockIdx.x;    // 0..62
  int cc = blockIdx.y;    // 0..7
  int tid = threadIdx.x;
  for (int i = tid; i < B_ * E_; i += 256) {
    int b = i >> 8, e = i & 255;
    x_lds[i] = emb[(size_t)target[b * 64 + t] * E_ + e];
  }
  __syncthreads();
  int col = cc * 256 + tid;
  float acc[B_];
#pragma unroll
  for (int b = 0; b < B_; ++b) acc[b] = 0.f;
  for (int e4 = 0; e4 < E_ / 4; ++e4) {
    float w0 = W_x[(size_t)(4 * e4 + 0) * FU_ + col];
    float w1 = W_x[(size_t)(4 * e4 + 1) * FU_ + col];
    float w2 = W_x[(size_t)(4 * e4 + 2) * FU_ + col];
    float w3 = W_x[(size_t)(4 * e4 + 3) * FU_ + col];
#pragma unroll
    for (int b = 0; b < B_; ++b) {
      f32x4 xv = *(const f32x4*)&x_lds[b * E_ + 4 * e4];
      acc[b] += xv[0] * w0 + xv[1] * w1 + xv[2] * w2 + xv[3] * w3;
    }
  }
  float bias = b_lstm[col];
#pragma unroll
  for (int b = 0; b < B_; ++b)
    Zx[((size_t)(t * B_ + b)) * FU_ + col] = acc[b] + bias;
}

// ---------------------------------------------------------------- k_encproj
__global__ __launch_bounds__(256) void k_encproj(const float* __restrict__ enc_out,
    const float* __restrict__ Wa, float* __restrict__ enc_proj) {
  __shared__ float e_lds[16 * U_];   // 32 KB
  int rc = blockIdx.x;   // 0..127 (16 rows each)
  int cc = blockIdx.y;   // 0..1
  int tid = threadIdx.x;
  int row0 = rc * 16;
  for (int i = tid; i < 16 * U_; i += 256)
    e_lds[i] = enc_out[(size_t)(row0 + (i >> 9)) * U_ + (i & 511)];
  __syncthreads();
  int col = cc * 256 + tid;
  float acc[16];
#pragma unroll
  for (int r = 0; r < 16; ++r) acc[r] = 0.f;
  for (int k4 = 0; k4 < U_ / 4; ++k4) {
    float w0 = Wa[(size_t)(4 * k4 + 0) * U_ + col];
    float w1 = Wa[(size_t)(4 * k4 + 1) * U_ + col];
    float w2 = Wa[(size_t)(4 * k4 + 2) * U_ + col];
    float w3 = Wa[(size_t)(4 * k4 + 3) * U_ + col];
#pragma unroll
    for (int r = 0; r < 16; ++r) {
      f32x4 xv = *(const f32x4*)&e_lds[r * U_ + 4 * k4];
      acc[r] += xv[0] * w0 + xv[1] * w1 + xv[2] * w2 + xv[3] * w3;
    }
  }
#pragma unroll
  for (int r = 0; r < 16; ++r)
    enc_proj[(size_t)(row0 + r) * U_ + col] = acc[r];
}

// ---------------------------------------------------------------- k_wfcT
__global__ __launch_bounds__(256) void k_wfcT(const float* __restrict__ W_fc,
                                              unsigned short* __restrict__ WfcT) {
  __shared__ float tile[32][33];
  int nb = blockIdx.x;   // 0..999
  int kb = blockIdx.y;   // 0..31
  int tid = threadIdx.x;
  int r = tid >> 5, c = tid & 31;
#pragma unroll
  for (int i = 0; i < 4; ++i)
    tile[r + 8 * i][c] = W_fc[(size_t)(kb * 32 + r + 8 * i) * V_ + nb * 32 + c];
  __syncthreads();
#pragma unroll
  for (int i = 0; i < 4; ++i)
    WfcT[(size_t)(nb * 32 + r + 8 * i) * KFC_ + kb * 32 + c] = f2bf(tile[c][r + 8 * i]);
}

// ---------------------------------------------------------------- k_rec
// 64 blocks x 256 threads, single launch, no grid barrier.
//   blocks 0..31  (g): LSTM producers — u-slice [g*16, g*16+16) of all 4 gates.
//   blocks 32..63 (b): attention consumers — batch element b, all 63 steps.
// h exchanged via LLC with relaxed agent-scope atomics (L2-bypass, no fences,
// so L2 locality of fragWh / enc_proj / enc_out survives across steps).
// hcnt[t] = number of producers that have published hseq[t] (monotone flags).
__global__ __launch_bounds__(256) void k_rec(const float* __restrict__ enc_out,
    const float* __restrict__ enc_h0, const float* __restrict__ enc_c0,
    const float* __restrict__ enc_proj, const float* __restrict__ Zx,
    const unsigned short* __restrict__ fragWh,
    unsigned int* hseq32,                  // 64 steps x (B_*U_/2) u32 (bf16 pairs)
    unsigned short* __restrict__ Afc,      // 2048 x 1024 bf16 [ctx | h]
    unsigned int* hcnt) {
  __shared__ unsigned short h_lds[B_ * 520];   // padded rows (1040B = 65*16B)
  __shared__ float z_lds[B_ * 64];
  __shared__ float c_lds[B_ * 16];
  __shared__ float h_sh[U_];
  __shared__ float sc_part[4 * L_];
  __shared__ float probs[L_];

  const int tid = threadIdx.x;
  unsigned long long* hseq64 = (unsigned long long*)hseq32;

  if (blockIdx.x < 32) {
    // ---------------- producer ----------------
    const int g = blockIdx.x;
    const int w = tid >> 6;
    const int lane = tid & 63;
    const int quad = lane >> 4;
    const int l15 = lane & 15;
    const int b = tid >> 3;      // gate-phase mapping: 32 b x 8 j
    const int j = tid & 7;       // u = g*16 + 2j, 2j+1

    // init: c slice -> LDS (fp32, persistent); h0 slice -> hseq[0]
    {
      int u = g * 16 + 2 * j;
      float h0a = enc_h0[(size_t)b * U_ + u];
      float h0b = enc_h0[(size_t)b * U_ + u + 1];
      unsigned pack = (unsigned)f2bf(h0a) | ((unsigned)f2bf(h0b) << 16);
      __hip_atomic_store(&hseq32[b * 256 + g * 8 + j], pack,
                         __ATOMIC_RELAXED, __HIP_MEMORY_SCOPE_AGENT);
      c_lds[b * 16 + 2 * j]     = enc_c0[(size_t)b * U_ + u];
      c_lds[b * 16 + 2 * j + 1] = enc_c0[(size_t)b * U_ + u + 1];
    }
    __syncthreads();
    if (tid == 0)
      __hip_atomic_fetch_add(&hcnt[0], 1u, __ATOMIC_RELEASE, __HIP_MEMORY_SCOPE_AGENT);

    for (int t = 0; t < T_; ++t) {
      // wait for h[t] fully published
      if (tid == 0) {
        while (__hip_atomic_load(&hcnt[t], __ATOMIC_RELAXED, __HIP_MEMORY_SCOPE_AGENT) < 32u)
          __builtin_amdgcn_s_sleep(1);
      }
      __syncthreads();

      // stage h[t] (32KB) LLC -> LDS via u64 atomic loads
      const unsigned long long* hp = hseq64 + (size_t)t * (B_ * U_ / 4);
#pragma unroll
      for (int i = 0; i < 16; ++i) {
        int idx = i * 256 + tid;            // 0..4095
        int hb = idx >> 7, u0 = (idx & 127) * 4;
        unsigned long long v = __hip_atomic_load(&hp[idx], __ATOMIC_RELAXED,
                                                 __HIP_MEMORY_SCOPE_AGENT);
        *(unsigned long long*)&h_lds[hb * 520 + u0] = v;
      }

      // prefetch Zx for the gate phase (overlaps with MFMA)
      const float* zxbase = Zx + ((size_t)(t * B_ + b)) * FU_ + g * 16 + 2 * j;
      f32x2 zx0 = *(const f32x2*)(zxbase + 0 * U_);
      f32x2 zx1 = *(const f32x2*)(zxbase + 1 * U_);
      f32x2 zx2 = *(const f32x2*)(zxbase + 2 * U_);
      f32x2 zx3 = *(const f32x2*)(zxbase + 3 * U_);
      __syncthreads();

      // z-slice = h @ W_h  (wave w -> gate w, cols w*512 + g*16 + [0,16))
      f32x4 acc0 = {0.f, 0.f, 0.f, 0.f}, acc1 = {0.f, 0.f, 0.f, 0.f};
      const unsigned short* bbase = fragWh + ((size_t)(w * 32 + g) * 16) * 64 * 8;
#pragma unroll
      for (int kc = 0; kc < 16; ++kc) {
        bf16x8 bf = *(const bf16x8*)(bbase + (size_t)(kc * 64 + lane) * 8);
        bf16x8 a0 = *(const bf16x8*)&h_lds[l15 * 520 + kc * 32 + quad * 8];
        bf16x8 a1 = *(const bf16x8*)&h_lds[(16 + l15) * 520 + kc * 32 + quad * 8];
        acc0 = __builtin_amdgcn_mfma_f32_16x16x32_bf16(a0, bf, acc0, 0, 0, 0);
        acc1 = __builtin_amdgcn_mfma_f32_16x16x32_bf16(a1, bf, acc1, 0, 0, 0);
      }
#pragma unroll
      for (int r = 0; r < 4; ++r) {
        z_lds[(quad * 4 + r) * 64 + w * 16 + l15] = acc0[r];
        z_lds[(16 + quad * 4 + r) * 64 + w * 16 + l15] = acc1[r];
      }
      __syncthreads();

      // gates + state update for (b, 2j) and (b, 2j+1)
      {
        int up0 = 2 * j, up1 = 2 * j + 1;
        float zi0 = z_lds[b * 64 + 0 + up0] + zx0[0];
        float zi1 = z_lds[b * 64 + 0 + up1] + zx0[1];
        float zf0 = z_lds[b * 64 + 16 + up0] + zx1[0];
        float zf1 = z_lds[b * 64 + 16 + up1] + zx1[1];
        float zg0 = z_lds[b * 64 + 32 + up0] + zx2[0];
        float zg1 = z_lds[b * 64 + 32 + up1] + zx2[1];
        float zo0 = z_lds[b * 64 + 48 + up0] + zx3[0];
        float zo1 = z_lds[b * 64 + 48 + up1] + zx3[1];
        float i0 = 1.f / (1.f + expf(-zi0)), i1 = 1.f / (1.f + expf(-zi1));
        float f0 = 1.f / (1.f + expf(-zf0)), f1 = 1.f / (1.f + expf(-zf1));
        float g0 = tanhf(zg0),               g1 = tanhf(zg1);
        float o0 = 1.f / (1.f + expf(-zo0)), o1 = 1.f / (1.f + expf(-zo1));
        float c0 = f0 * c_lds[b * 16 + up0] + i0 * g0;
        float c1 = f1 * c_lds[b * 16 + up1] + i1 * g1;
        c_lds[b * 16 + up0] = c0;
        c_lds[b * 16 + up1] = c1;
        float h0 = o0 * tanhf(c0);
        float h1 = o1 * tanhf(c1);
        unsigned pack = (unsigned)f2bf(h0) | ((unsigned)f2bf(h1) << 16);
        // publish h[t+1] (LLC write-through)
        __hip_atomic_store(&hseq32[(size_t)(t + 1) * (B_ * U_ / 2) + b * 256 + g * 8 + j],
                           pack, __ATOMIC_RELAXED, __HIP_MEMORY_SCOPE_AGENT);
        // h-half of Afc (plain store; consumed by a later kernel)
        *(unsigned*)&Afc[(size_t)(t * B_ + b) * KFC_ + U_ + g * 16 + 2 * j] = pack;
      }
      __syncthreads();
      if (tid == 0)
        __hip_atomic_fetch_add(&hcnt[t + 1], 1u, __ATOMIC_RELEASE, __HIP_MEMORY_SCOPE_AGENT);
    }
  } else {
    // ---------------- consumer: attention for batch b ----------------
    const int b = blockIdx.x - 32;
    for (int t = 0; t < T_; ++t) {
      if (tid == 0) {
        while (__hip_atomic_load(&hcnt[t + 1], __ATOMIC_RELAXED, __HIP_MEMORY_SCOPE_AGENT) < 32u)
          __builtin_amdgcn_s_sleep(8);
      }
      __syncthreads();
      // read h[t+1][b] (512 bf16 = 128 u64)
      if (tid < 128) {
        unsigned long long v = __hip_atomic_load(
            &hseq64[(size_t)(t + 1) * (B_ * U_ / 4) + b * 128 + tid],
            __ATOMIC_RELAXED, __HIP_MEMORY_SCOPE_AGENT);
        int u0 = tid * 4;
        h_sh[u0 + 0] = bf2f((unsigned short)(v & 0xFFFFu));
        h_sh[u0 + 1] = bf2f((unsigned short)((v >> 16) & 0xFFFFu));
        h_sh[u0 + 2] = bf2f((unsigned short)((v >> 32) & 0xFFFFu));
        h_sh[u0 + 3] = bf2f((unsigned short)((v >> 48) & 0xFFFFu));
      }
      __syncthreads();
      // score[l] = h . enc_proj[b,l,:]
      {
        int l = tid & 63, part = tid >> 6;
        const float* ep = enc_proj + ((size_t)(b * L_ + l)) * U_ + part * 128;
        const float* hs = h_sh + part * 128;
        float s = 0.f;
#pragma unroll 8
        for (int u = 0; u < 128; u += 4) {
          f32x4 e = *(const f32x4*)(ep + u);
          s += hs[u] * e[0] + hs[u + 1] * e[1] + hs[u + 2] * e[2] + hs[u + 3] * e[3];
        }
        sc_part[part * L_ + l] = s;
      }
      __syncthreads();
      if (tid < 64) {
        float s = sc_part[tid] + sc_part[64 + tid] + sc_part[128 + tid] + sc_part[192 + tid];
        float m = s;
#pragma unroll
        for (int off = 32; off >= 1; off >>= 1) m = fmaxf(m, __shfl_xor(m, off));
        float e = expf(s - m);
        float sum = e;
#pragma unroll
        for (int off = 32; off >= 1; off >>= 1) sum += __shfl_xor(sum, off);
        probs[tid] = e / sum;
      }
      __syncthreads();
      // ctx = attn^T enc_out[b]; write ctx-half of Afc
      for (int u = tid; u < U_; u += 256) {
        float c = 0.f;
        const float* eo = enc_out + ((size_t)b * L_) * U_ + u;
#pragma unroll 16
        for (int l = 0; l < L_; ++l) c += probs[l] * eo[(size_t)l * U_];
        Afc[(size_t)(t * B_ + b) * KFC_ + u] = f2bf(c);
      }
      __syncthreads();
    }
  }
}

// ---------------------------------------------------------------- k_fc
// (2016x1024) @ (1024x32000) bf16 MFMA, fused tanh(+bias) + per-row sum(exp) atomics.
__global__ __launch_bounds__(256) void k_fc(const unsigned short* __restrict__ Afc,
    const unsigned short* __restrict__ WfcT, const float* __restrict__ b_fc,
    float* __restrict__ out, float* __restrict__ row_sums) {
  __shared__ unsigned short At[128 * 32];
  __shared__ unsigned short Bt[128 * 32];
  __shared__ float rs[128];
  const int tid = threadIdx.x;
  const int w = tid >> 6, lane = tid & 63, quad = lane >> 4, l15 = lane & 15;
  const int row0 = blockIdx.y * 128, col0 = blockIdx.x * 128;
  const int mh = (w >> 1) * 64, nh = (w & 1) * 64;

  f32x4 acc[4][4];
#pragma unroll
  for (int i = 0; i < 4; ++i)
#pragma unroll
    for (int j = 0; j < 4; ++j) { f32x4 z = {0.f, 0.f, 0.f, 0.f}; acc[i][j] = z; }

  for (int kt = 0; kt < KFC_ / 32; ++kt) {
    int k0 = kt * 32;
#pragma unroll
    for (int i = 0; i < 2; ++i) {
      int lin = i * 256 + tid;
      int r = lin >> 2, s = lin & 3;
      int gseg = (s - (r >> 1)) & 3;     // XOR swizzle
      f32x4 va = *(const f32x4*)(Afc + ((size_t)(row0 + r)) * KFC_ + k0 + gseg * 8);
      *(f32x4*)&At[r * 32 + s * 8] = va;
      f32x4 vb = *(const f32x4*)(WfcT + ((size_t)(col0 + r)) * KFC_ + k0 + gseg * 8);
      *(f32x4*)&Bt[r * 32 + s * 8] = vb;
    }
    __syncthreads();
    bf16x8 a[4], b[4];
#pragma unroll
    for (int i = 0; i < 4; ++i) {
      int m = mh + i * 16 + l15;
      a[i] = *(const bf16x8*)&At[m * 32 + (((quad + (m >> 1)) & 3) * 8)];
      int n = nh + i * 16 + l15;
      b[i] = *(const bf16x8*)&Bt[n * 32 + (((quad + (n >> 1)) & 3) * 8)];
    }
#pragma unroll
    for (int i = 0; i < 4; ++i)
#pragma unroll
      for (int j = 0; j < 4; ++j)
        acc[i][j] = __builtin_amdgcn_mfma_f32_16x16x32_bf16(a[i], b[j], acc[i][j], 0, 0, 0);
    __syncthreads();
  }

  if (tid < 128) rs[tid] = 0.f;
  __syncthreads();
  float bv[4];
#pragma unroll
  for (int j = 0; j < 4; ++j) bv[j] = b_fc[col0 + nh + j * 16 + l15];
  float rp[4][4];
#pragma unroll
  for (int i = 0; i < 4; ++i)
#pragma unroll
    for (int r = 0; r < 4; ++r) rp[i][r] = 0.f;
#pragma unroll
  for (int i = 0; i < 4; ++i) {
#pragma unroll
    for (int j = 0; j < 4; ++j) {
      int cg = col0 + nh + j * 16 + l15;
#pragma unroll
      for (int r = 0; r < 4; ++r) {
        float val = tanhf(acc[i][j][r] + bv[j]);
        int rg = row0 + mh + i * 16 + quad * 4 + r;
        if (rg < MROW_) {
          int b = rg & 31, t = rg >> 5;
          out[((size_t)(b * T_ + t)) * V_ + cg] = val;
        }
        rp[i][r] += expf(val);
      }
    }
  }
#pragma unroll
  for (int i = 0; i < 4; ++i)
#pragma unroll
    for (int r = 0; r < 4; ++r) {
      float v = rp[i][r];
      v += __shfl_xor(v, 1); v += __shfl_xor(v, 2);
      v += __shfl_xor(v, 4); v += __shfl_xor(v, 8);
      if (l15 == 0) atomicAdd(&rs[mh + i * 16 + quad * 4 + r], v);
    }
  __syncthreads();
  if (tid < 128) {
    int rg = row0 + tid;
    if (rg < MROW_) atomicAdd(&row_sums[rg], rs[tid]);
  }
}

// ---------------------------------------------------------------- k_lsm
__global__ __launch_bounds__(256) void k_lsm(float* __restrict__ out,
                                             const float* __restrict__ row_sums, int n4) {
  int i = blockIdx.x * 256 + threadIdx.x;
  if (i >= n4) return;
  f32x4* o4 = (f32x4*)out;
  f32x4 v = o4[i];
  int r = i / 8000;              // V/4 = 8000 vec4 per row; row = b*63 + t
  int b = r / 63, t = r - b * 63;
  float ls = logf(row_sums[t * 32 + b]);
  v[0] -= ls; v[1] -= ls; v[2] -= ls; v[3] -= ls;
  o4[i] = v;
}

// ---------------------------------------------------------------- launch
extern "C" void kernel_launch(void* const* d_in, const int* in_sizes, int n_in,
                              void* d_out, int out_size, void* d_ws, size_t ws_size,
                              hipStream_t stream) {
  const int*   target  = (const int*)d_in[0];
  const float* enc_out = (const float*)d_in[1];
  const float* enc_h0  = (const float*)d_in[2];
  const float* enc_c0  = (const float*)d_in[3];
  const float* emb     = (const float*)d_in[4];
  const float* W_x     = (const float*)d_in[5];
  const float* W_h     = (const float*)d_in[6];
  const float* b_lstm  = (const float*)d_in[7];
  const float* Wa      = (const float*)d_in[8];
  const float* W_fc    = (const float*)d_in[9];
  const float* b_fc    = (const float*)d_in[10];
  float* out = (float*)d_out;
  char* ws = (char*)d_ws;

  // ws layout (bytes); total ~90.3 MiB
  unsigned int*   hcnt     = (unsigned int*)(ws + 0);             // 64 u32
  float*          row_sums = (float*)(ws + 1024);                 // 2016 f32
  unsigned short* fragWh   = (unsigned short*)(ws + 16384);       // 2 MiB
  unsigned int*   hseq32   = (unsigned int*)(ws + 2113536);       // 2 MiB (64 steps)
  float*          Zx       = (float*)(ws + 4210688);              // 16.5 MB
  float*          enc_proj = (float*)(ws + 20725760);             // 4 MiB
  unsigned short* Afc      = (unsigned short*)(ws + 24920064);    // 4 MiB (2048x1024)
  unsigned short* WfcT     = (unsigned short*)(ws + 29114368);    // 62.5 MiB

  k_zero   <<<dim3(8),          dim3(256), 0, stream>>>(hcnt, row_sums);
  k_fragWh <<<dim3(512),        dim3(256), 0, stream>>>(W_h, fragWh);
  k_zx     <<<dim3(63, 8),      dim3(256), 0, stream>>>(target, emb, W_x, b_lstm, Zx);
  k_encproj<<<dim3(128, 2),     dim3(256), 0, stream>>>(enc_out, Wa, enc_proj);
  k_wfcT   <<<dim3(1000, 32),   dim3(256), 0, stream>>>(W_fc, WfcT);
  k_rec    <<<dim3(64),         dim3(256), 0, stream>>>(enc_out, enc_h0, enc_c0,
                                                        enc_proj, Zx, fragWh,
                                                        hseq32, Afc, hcnt);
  k_fc     <<<dim3(250, 16),    dim3(256), 0, stream>>>(Afc, WfcT, b_fc, out, row_sums);
  k_lsm    <<<dim3(63000),      dim3(256), 0, stream>>>(out, row_sums, 16128000);
}

// Round 3
// 1288.491 us; speedup vs baseline: 1.2902x; 1.0662x over previous
//
#include <hip/hip_runtime.h>
#include <stdint.h>

// Problem constants (from reference)
#define B_   32
#define T_   63      // S-1
#define U_   512
#define E_   256
#define V_   32000
#define L_   64
#define FU_  2048    // 4U
#define KFC_ 1024    // 2U
#define MROW_ 2016   // B*T

typedef float f32x4 __attribute__((ext_vector_type(4)));
typedef float f32x2 __attribute__((ext_vector_type(2)));
typedef __bf16 bf16x8 __attribute__((ext_vector_type(8)));

__device__ __forceinline__ unsigned short f2bf(float f) {
  union { float f; unsigned u; } v; v.f = f;
  unsigned u = v.u;
  u += 0x7FFFu + ((u >> 16) & 1u);   // round-to-nearest-even
  return (unsigned short)(u >> 16);
}
__device__ __forceinline__ float bf2f(unsigned short h) {
  union { unsigned u; float f; } v; v.u = ((unsigned)h) << 16;
  return v.f;
}
__device__ __forceinline__ float fast_sigmoid(float x) {
  return 1.f / (1.f + __expf(-x));
}
__device__ __forceinline__ float fast_tanh(float x) {
  float e = __expf(2.f * x);          // x>>0: e=inf -> 1; x<<0: e=0 -> -1
  return 1.f - 2.f / (e + 1.f);
}

// ---------------------------------------------------------------- k_zero
__global__ __launch_bounds__(256) void k_zero(unsigned int* hcnt, float* row_sums) {
  int i = blockIdx.x * 256 + threadIdx.x;
  if (i < 1024) hcnt[i] = 0u;                    // flags padded: one per 16 u32
  if (i < MROW_) row_sums[i] = 0.f;
}

// ---------------------------------------------------------------- k_fragWh
// fragWh[ct][kc][lane][j] = bf16(W_h[kc*32 + (lane>>4)*8 + j][ct*16 + (lane&15)])
__global__ __launch_bounds__(256) void k_fragWh(const float* __restrict__ W_h,
                                                unsigned short* __restrict__ fragWh) {
  int idx = blockIdx.x * 256 + threadIdx.x;   // 0..131071 = 128ct * 16kc * 64lane
  int lane = idx & 63;
  int kc   = (idx >> 6) & 15;
  int ct   = idx >> 10;
  int quad = lane >> 4, l15 = lane & 15;
  int col = ct * 16 + l15;
  unsigned short* dst = fragWh + (size_t)idx * 8;
#pragma unroll
  for (int j = 0; j < 8; ++j) {
    int k = kc * 32 + quad * 8 + j;
    dst[j] = f2bf(W_h[(size_t)k * FU_ + col]);
  }
}

// ---------------------------------------------------------------- k_zx
// Zx[t][b][col] = bf16(emb[target[b,t]] @ W_x + b_lstm)
__global__ __launch_bounds__(256) void k_zx(const int* __restrict__ target,
    const float* __restrict__ emb, const float* __restrict__ W_x,
    const float* __restrict__ b_lstm, unsigned short* __restrict__ Zx) {
  __shared__ float x_lds[B_ * E_];   // 32 KB
  int t  = blockIdx.x;    // 0..62
  int cc = blockIdx.y;    // 0..7
  int tid = threadIdx.x;
  for (int i = tid; i < B_ * E_; i += 256) {
    int b = i >> 8, e = i & 255;
    x_lds[i] = emb[(size_t)target[b * 64 + t] * E_ + e];
  }
  __syncthreads();
  int col = cc * 256 + tid;
  float acc[B_];
#pragma unroll
  for (int b = 0; b < B_; ++b) acc[b] = 0.f;
  for (int e4 = 0; e4 < E_ / 4; ++e4) {
    float w0 = W_x[(size_t)(4 * e4 + 0) * FU_ + col];
    float w1 = W_x[(size_t)(4 * e4 + 1) * FU_ + col];
    float w2 = W_x[(size_t)(4 * e4 + 2) * FU_ + col];
    float w3 = W_x[(size_t)(4 * e4 + 3) * FU_ + col];
#pragma unroll
    for (int b = 0; b < B_; ++b) {
      f32x4 xv = *(const f32x4*)&x_lds[b * E_ + 4 * e4];
      acc[b] += xv[0] * w0 + xv[1] * w1 + xv[2] * w2 + xv[3] * w3;
    }
  }
  float bias = b_lstm[col];
#pragma unroll
  for (int b = 0; b < B_; ++b)
    Zx[((size_t)(t * B_ + b)) * FU_ + col] = f2bf(acc[b] + bias);
}

// ---------------------------------------------------------------- k_encproj
__global__ __launch_bounds__(256) void k_encproj(const float* __restrict__ enc_out,
    const float* __restrict__ Wa, float* __restrict__ enc_proj) {
  __shared__ float e_lds[16 * U_];   // 32 KB
  int rc = blockIdx.x;   // 0..127 (16 rows each)
  int cc = blockIdx.y;   // 0..1
  int tid = threadIdx.x;
  int row0 = rc * 16;
  for (int i = tid; i < 16 * U_; i += 256)
    e_lds[i] = enc_out[(size_t)(row0 + (i >> 9)) * U_ + (i & 511)];
  __syncthreads();
  int col = cc * 256 + tid;
  float acc[16];
#pragma unroll
  for (int r = 0; r < 16; ++r) acc[r] = 0.f;
  for (int k4 = 0; k4 < U_ / 4; ++k4) {
    float w0 = Wa[(size_t)(4 * k4 + 0) * U_ + col];
    float w1 = Wa[(size_t)(4 * k4 + 1) * U_ + col];
    float w2 = Wa[(size_t)(4 * k4 + 2) * U_ + col];
    float w3 = Wa[(size_t)(4 * k4 + 3) * U_ + col];
#pragma unroll
    for (int r = 0; r < 16; ++r) {
      f32x4 xv = *(const f32x4*)&e_lds[r * U_ + 4 * k4];
      acc[r] += xv[0] * w0 + xv[1] * w1 + xv[2] * w2 + xv[3] * w3;
    }
  }
#pragma unroll
  for (int r = 0; r < 16; ++r)
    enc_proj[(size_t)(row0 + r) * U_ + col] = acc[r];
}

// ---------------------------------------------------------------- k_encT
// encT[b][u][l] = bf16(enc_out[b][l][u])   (for the attention ctx loop)
__global__ __launch_bounds__(256) void k_encT(const float* __restrict__ enc_out,
                                              unsigned short* __restrict__ encT) {
  __shared__ float tile[64][65];
  int b  = blockIdx.x;   // 0..31
  int uc = blockIdx.y;   // 0..7
  int tid = threadIdx.x;
#pragma unroll
  for (int i = 0; i < 16; ++i) {
    int idx = i * 256 + tid;            // 0..4095
    int l = idx >> 6, u = idx & 63;
    tile[l][u] = enc_out[((size_t)b * L_ + l) * U_ + uc * 64 + u];
  }
  __syncthreads();
#pragma unroll
  for (int i = 0; i < 16; ++i) {
    int idx = i * 256 + tid;
    int u = idx >> 6, l = idx & 63;
    encT[((size_t)b * U_ + uc * 64 + u) * L_ + l] = f2bf(tile[l][u]);
  }
}

// ---------------------------------------------------------------- k_wfcT
__global__ __launch_bounds__(256) void k_wfcT(const float* __restrict__ W_fc,
                                              unsigned short* __restrict__ WfcT) {
  __shared__ float tile[32][33];
  int nb = blockIdx.x;   // 0..999
  int kb = blockIdx.y;   // 0..31
  int tid = threadIdx.x;
  int r = tid >> 5, c = tid & 31;
#pragma unroll
  for (int i = 0; i < 4; ++i)
    tile[r + 8 * i][c] = W_fc[(size_t)(kb * 32 + r + 8 * i) * V_ + nb * 32 + c];
  __syncthreads();
#pragma unroll
  for (int i = 0; i < 4; ++i)
    WfcT[(size_t)(nb * 32 + r + 8 * i) * KFC_ + kb * 32 + c] = f2bf(tile[c][r + 8 * i]);
}

// ---------------------------------------------------------------- k_rec
// 64 blocks x 256 threads, single launch.
//   blocks 0..31  (g): LSTM producers — u-slice [g*16, g*16+16) of all 4 gates.
//   blocks 32..63 (b): attention consumers — batch element b, all 63 steps.
// h exchanged via LLC with relaxed agent-scope atomics. Publish ordering:
// __syncthreads() drains each thread's vmcnt(0) (h stores complete at LLC),
// then a RELAXED fetch_add on the padded flag — no buffer_wbl2 on the path.
__global__ __launch_bounds__(256, 1) void k_rec(const float* __restrict__ enc_h0,
    const float* __restrict__ enc_c0,
    const float* __restrict__ enc_proj, const unsigned short* __restrict__ Zx,
    const unsigned short* __restrict__ fragWh, const unsigned short* __restrict__ encT,
    unsigned int* hseq32,                  // 64 steps x (B_*U_/2) u32 (bf16 pairs)
    unsigned short* __restrict__ Afc,      // 2048 x 1024 bf16 [ctx | h]
    unsigned int* hcnt) {                  // flags at hcnt[t*16]
  __shared__ unsigned short h_lds[B_ * 520];   // padded rows (1040B)
  __shared__ float z_lds[B_ * 68];
  __shared__ float c_lds[B_ * 17];
  __shared__ float h_sh[U_];
  __shared__ float sc_part[4 * L_];
  __shared__ float probs[L_];

  const int tid = threadIdx.x;
  unsigned long long* hseq64 = (unsigned long long*)hseq32;

  if (blockIdx.x < 32) {
    // ---------------- producer ----------------
    const int g = blockIdx.x;
    const int w = tid >> 6;
    const int lane = tid & 63;
    const int quad = lane >> 4;
    const int l15 = lane & 15;
    const int b = tid >> 3;      // gate-phase mapping: 32 b x 8 j
    const int j = tid & 7;       // u = g*16 + 2j, 2j+1

    // hoist step-invariant W_h B-fragments into registers (64 VGPRs)
    const unsigned short* bbase = fragWh + ((size_t)(w * 32 + g) * 16) * 64 * 8;
    bf16x8 bfr[16];
#pragma unroll
    for (int kc = 0; kc < 16; ++kc)
      bfr[kc] = *(const bf16x8*)(bbase + (size_t)(kc * 64 + lane) * 8);

    // init: c slice -> LDS (fp32, persistent); h0 slice -> hseq[0]
    {
      int u = g * 16 + 2 * j;
      float h0a = enc_h0[(size_t)b * U_ + u];
      float h0b = enc_h0[(size_t)b * U_ + u + 1];
      unsigned pack = (unsigned)f2bf(h0a) | ((unsigned)f2bf(h0b) << 16);
      __hip_atomic_store(&hseq32[b * 256 + g * 8 + j], pack,
                         __ATOMIC_RELAXED, __HIP_MEMORY_SCOPE_AGENT);
      c_lds[b * 17 + 2 * j]     = enc_c0[(size_t)b * U_ + u];
      c_lds[b * 17 + 2 * j + 1] = enc_c0[(size_t)b * U_ + u + 1];
    }
    __syncthreads();   // drains vmcnt(0): h0 stores complete at LLC
    if (tid == 0)
      __hip_atomic_fetch_add(&hcnt[0], 1u, __ATOMIC_RELAXED, __HIP_MEMORY_SCOPE_AGENT);

    for (int t = 0; t < T_; ++t) {
      // prefetch Zx (bf16, independent of the flag) — 4 u32, one per gate
      const unsigned short* zxbase = Zx + ((size_t)(t * B_ + b)) * FU_ + g * 16 + 2 * j;
      unsigned zxp0 = *(const unsigned*)(zxbase + 0 * U_);
      unsigned zxp1 = *(const unsigned*)(zxbase + 1 * U_);
      unsigned zxp2 = *(const unsigned*)(zxbase + 2 * U_);
      unsigned zxp3 = *(const unsigned*)(zxbase + 3 * U_);

      // wait for h[t] fully published
      if (tid == 0) {
        while (__hip_atomic_load(&hcnt[t * 16], __ATOMIC_RELAXED,
                                 __HIP_MEMORY_SCOPE_AGENT) < 32u)
          __builtin_amdgcn_s_sleep(1);
      }
      __syncthreads();

      // stage h[t] (32KB) LLC -> LDS via u64 atomic loads (coalesced per row)
      const unsigned long long* hp = hseq64 + (size_t)t * (B_ * U_ / 4);
#pragma unroll
      for (int i = 0; i < 16; ++i) {
        int idx = i * 256 + tid;            // 0..4095
        int hb = idx >> 7, u0 = (idx & 127) * 4;
        unsigned long long v = __hip_atomic_load(&hp[idx], __ATOMIC_RELAXED,
                                                 __HIP_MEMORY_SCOPE_AGENT);
        *(unsigned long long*)&h_lds[hb * 520 + u0] = v;
      }
      __syncthreads();

      // z-slice = h @ W_h  (wave w -> gate w, cols w*512 + g*16 + [0,16))
      f32x4 acc0 = {0.f, 0.f, 0.f, 0.f}, acc1 = {0.f, 0.f, 0.f, 0.f};
#pragma unroll
      for (int kc = 0; kc < 16; ++kc) {
        bf16x8 a0 = *(const bf16x8*)&h_lds[l15 * 520 + kc * 32 + quad * 8];
        bf16x8 a1 = *(const bf16x8*)&h_lds[(16 + l15) * 520 + kc * 32 + quad * 8];
        acc0 = __builtin_amdgcn_mfma_f32_16x16x32_bf16(a0, bfr[kc], acc0, 0, 0, 0);
        acc1 = __builtin_amdgcn_mfma_f32_16x16x32_bf16(a1, bfr[kc], acc1, 0, 0, 0);
      }
#pragma unroll
      for (int r = 0; r < 4; ++r) {
        z_lds[(quad * 4 + r) * 68 + w * 16 + l15] = acc0[r];
        z_lds[(16 + quad * 4 + r) * 68 + w * 16 + l15] = acc1[r];
      }
      __syncthreads();

      // gates + state update for (b, 2j) and (b, 2j+1)
      {
        int up0 = 2 * j, up1 = 2 * j + 1;
        float zi0 = z_lds[b * 68 + 0 + up0] + bf2f((unsigned short)(zxp0 & 0xFFFFu));
        float zi1 = z_lds[b * 68 + 0 + up1] + bf2f((unsigned short)(zxp0 >> 16));
        float zf0 = z_lds[b * 68 + 16 + up0] + bf2f((unsigned short)(zxp1 & 0xFFFFu));
        float zf1 = z_lds[b * 68 + 16 + up1] + bf2f((unsigned short)(zxp1 >> 16));
        float zg0 = z_lds[b * 68 + 32 + up0] + bf2f((unsigned short)(zxp2 & 0xFFFFu));
        float zg1 = z_lds[b * 68 + 32 + up1] + bf2f((unsigned short)(zxp2 >> 16));
        float zo0 = z_lds[b * 68 + 48 + up0] + bf2f((unsigned short)(zxp3 & 0xFFFFu));
        float zo1 = z_lds[b * 68 + 48 + up1] + bf2f((unsigned short)(zxp3 >> 16));
        float i0 = fast_sigmoid(zi0), i1 = fast_sigmoid(zi1);
        float f0 = fast_sigmoid(zf0), f1 = fast_sigmoid(zf1);
        float g0 = fast_tanh(zg0),    g1 = fast_tanh(zg1);
        float o0 = fast_sigmoid(zo0), o1 = fast_sigmoid(zo1);
        float c0 = f0 * c_lds[b * 17 + up0] + i0 * g0;
        float c1 = f1 * c_lds[b * 17 + up1] + i1 * g1;
        c_lds[b * 17 + up0] = c0;
        c_lds[b * 17 + up1] = c1;
        float h0 = o0 * fast_tanh(c0);
        float h1 = o1 * fast_tanh(c1);
        unsigned pack = (unsigned)f2bf(h0) | ((unsigned)f2bf(h1) << 16);
        __hip_atomic_store(&hseq32[(size_t)(t + 1) * (B_ * U_ / 2) + b * 256 + g * 8 + j],
                           pack, __ATOMIC_RELAXED, __HIP_MEMORY_SCOPE_AGENT);
        *(unsigned*)&Afc[(size_t)(t * B_ + b) * KFC_ + U_ + g * 16 + 2 * j] = pack;
      }
      __syncthreads();   // drains vmcnt(0): publish stores complete at LLC
      if (tid == 0)
        __hip_atomic_fetch_add(&hcnt[(t + 1) * 16], 1u,
                               __ATOMIC_RELAXED, __HIP_MEMORY_SCOPE_AGENT);
    }
  } else {
    // ---------------- consumer: attention for batch b ----------------
    const int b = blockIdx.x - 32;
    for (int t = 0; t < T_; ++t) {
      if (tid == 0) {
        while (__hip_atomic_load(&hcnt[(t + 1) * 16], __ATOMIC_RELAXED,
                                 __HIP_MEMORY_SCOPE_AGENT) < 32u)
          __builtin_amdgcn_s_sleep(2);
      }
      __syncthreads();
      // read h[t+1][b] (512 bf16 = 128 u64)
      if (tid < 128) {
        unsigned long long v = __hip_atomic_load(
            &hseq64[(size_t)(t + 1) * (B_ * U_ / 4) + b * 128 + tid],
            __ATOMIC_RELAXED, __HIP_MEMORY_SCOPE_AGENT);
        int u0 = tid * 4;
        h_sh[u0 + 0] = bf2f((unsigned short)(v & 0xFFFFu));
        h_sh[u0 + 1] = bf2f((unsigned short)((v >> 16) & 0xFFFFu));
        h_sh[u0 + 2] = bf2f((unsigned short)((v >> 32) & 0xFFFFu));
        h_sh[u0 + 3] = bf2f((unsigned short)((v >> 48) & 0xFFFFu));
      }
      __syncthreads();
      // score[l] = h . enc_proj[b,l,:]
      {
        int l = tid & 63, part = tid >> 6;
        const float* ep = enc_proj + ((size_t)(b * L_ + l)) * U_ + part * 128;
        const float* hs = h_sh + part * 128;
        float s = 0.f;
#pragma unroll 8
        for (int u = 0; u < 128; u += 4) {
          f32x4 e = *(const f32x4*)(ep + u);
          s += hs[u] * e[0] + hs[u + 1] * e[1] + hs[u + 2] * e[2] + hs[u + 3] * e[3];
        }
        sc_part[part * L_ + l] = s;
      }
      __syncthreads();
      if (tid < 64) {
        float s = sc_part[tid] + sc_part[64 + tid] + sc_part[128 + tid] + sc_part[192 + tid];
        float m = s;
#pragma unroll
        for (int off = 32; off >= 1; off >>= 1) m = fmaxf(m, __shfl_xor(m, off));
        float e = __expf(s - m);
        float sum = e;
#pragma unroll
        for (int off = 32; off >= 1; off >>= 1) sum += __shfl_xor(sum, off);
        probs[tid] = e / sum;
      }
      __syncthreads();
      // ctx = attn^T enc_out[b] via encT (contiguous per u); write ctx-half of Afc
      for (int u = tid; u < U_; u += 256) {
        const unsigned short* ep = encT + ((size_t)b * U_ + u) * L_;
        float c = 0.f;
#pragma unroll
        for (int l8 = 0; l8 < 8; ++l8) {
          bf16x8 e = *(const bf16x8*)(ep + l8 * 8);
#pragma unroll
          for (int q = 0; q < 8; ++q) c += probs[l8 * 8 + q] * (float)e[q];
        }
        Afc[(size_t)(t * B_ + b) * KFC_ + u] = f2bf(c);
      }
      __syncthreads();
    }
  }
}

// ---------------------------------------------------------------- k_fc
// (2016x1024) @ (1024x32000) bf16 MFMA, fused tanh(+bias) + per-row sum(exp) atomics.
__global__ __launch_bounds__(256) void k_fc(const unsigned short* __restrict__ Afc,
    const unsigned short* __restrict__ WfcT, const float* __restrict__ b_fc,
    float* __restrict__ out, float* __restrict__ row_sums) {
  __shared__ unsigned short At[128 * 32];
  __shared__ unsigned short Bt[128 * 32];
  __shared__ float rs[128];
  const int tid = threadIdx.x;
  const int w = tid >> 6, lane = tid & 63, quad = lane >> 4, l15 = lane & 15;
  const int row0 = blockIdx.y * 128, col0 = blockIdx.x * 128;
  const int mh = (w >> 1) * 64, nh = (w & 1) * 64;

  f32x4 acc[4][4];
#pragma unroll
  for (int i = 0; i < 4; ++i)
#pragma unroll
    for (int j = 0; j < 4; ++j) { f32x4 z = {0.f, 0.f, 0.f, 0.f}; acc[i][j] = z; }

  for (int kt = 0; kt < KFC_ / 32; ++kt) {
    int k0 = kt * 32;
#pragma unroll
    for (int i = 0; i < 2; ++i) {
      int lin = i * 256 + tid;
      int r = lin >> 2, s = lin & 3;
      int gseg = (s - (r >> 1)) & 3;     // XOR swizzle
      f32x4 va = *(const f32x4*)(Afc + ((size_t)(row0 + r)) * KFC_ + k0 + gseg * 8);
      *(f32x4*)&At[r * 32 + s * 8] = va;
      f32x4 vb = *(const f32x4*)(WfcT + ((size_t)(col0 + r)) * KFC_ + k0 + gseg * 8);
      *(f32x4*)&Bt[r * 32 + s * 8] = vb;
    }
    __syncthreads();
    bf16x8 a[4], b[4];
#pragma unroll
    for (int i = 0; i < 4; ++i) {
      int m = mh + i * 16 + l15;
      a[i] = *(const bf16x8*)&At[m * 32 + (((quad + (m >> 1)) & 3) * 8)];
      int n = nh + i * 16 + l15;
      b[i] = *(const bf16x8*)&Bt[n * 32 + (((quad + (n >> 1)) & 3) * 8)];
    }
#pragma unroll
    for (int i = 0; i < 4; ++i)
#pragma unroll
      for (int j = 0; j < 4; ++j)
        acc[i][j] = __builtin_amdgcn_mfma_f32_16x16x32_bf16(a[i], b[j], acc[i][j], 0, 0, 0);
    __syncthreads();
  }

  if (tid < 128) rs[tid] = 0.f;
  __syncthreads();
  float bv[4];
#pragma unroll
  for (int j = 0; j < 4; ++j) bv[j] = b_fc[col0 + nh + j * 16 + l15];
  float rp[4][4];
#pragma unroll
  for (int i = 0; i < 4; ++i)
#pragma unroll
    for (int r = 0; r < 4; ++r) rp[i][r] = 0.f;
#pragma unroll
  for (int i = 0; i < 4; ++i) {
#pragma unroll
    for (int j = 0; j < 4; ++j) {
      int cg = col0 + nh + j * 16 + l15;
#pragma unroll
      for (int r = 0; r < 4; ++r) {
        float val = fast_tanh(acc[i][j][r] + bv[j]);
        int rg = row0 + mh + i * 16 + quad * 4 + r;
        if (rg < MROW_) {
          int b = rg & 31, t = rg >> 5;
          out[((size_t)(b * T_ + t)) * V_ + cg] = val;
        }
        rp[i][r] += __expf(val);
      }
    }
  }
#pragma unroll
  for (int i = 0; i < 4; ++i)
#pragma unroll
    for (int r = 0; r < 4; ++r) {
      float v = rp[i][r];
      v += __shfl_xor(v, 1); v += __shfl_xor(v, 2);
      v += __shfl_xor(v, 4); v += __shfl_xor(v, 8);
      if (l15 == 0) atomicAdd(&rs[mh + i * 16 + quad * 4 + r], v);
    }
  __syncthreads();
  if (tid < 128) {
    int rg = row0 + tid;
    if (rg < MROW_) atomicAdd(&row_sums[rg], rs[tid]);
  }
}

// ---------------------------------------------------------------- k_lsm
__global__ __launch_bounds__(256) void k_lsm(float* __restrict__ out,
                                             const float* __restrict__ row_sums, int n4) {
  int i = blockIdx.x * 256 + threadIdx.x;
  if (i >= n4) return;
  f32x4* o4 = (f32x4*)out;
  f32x4 v = o4[i];
  int r = i / 8000;              // V/4 = 8000 vec4 per row; row = b*63 + t
  int b = r / 63, t = r - b * 63;
  float ls = __logf(row_sums[t * 32 + b]);
  v[0] -= ls; v[1] -= ls; v[2] -= ls; v[3] -= ls;
  o4[i] = v;
}

// ---------------------------------------------------------------- launch
extern "C" void kernel_launch(void* const* d_in, const int* in_sizes, int n_in,
                              void* d_out, int out_size, void* d_ws, size_t ws_size,
                              hipStream_t stream) {
  const int*   target  = (const int*)d_in[0];
  const float* enc_out = (const float*)d_in[1];
  const float* enc_h0  = (const float*)d_in[2];
  const float* enc_c0  = (const float*)d_in[3];
  const float* emb     = (const float*)d_in[4];
  const float* W_x     = (const float*)d_in[5];
  const float* W_h     = (const float*)d_in[6];
  const float* b_lstm  = (const float*)d_in[7];
  const float* Wa      = (const float*)d_in[8];
  const float* W_fc    = (const float*)d_in[9];
  const float* b_fc    = (const float*)d_in[10];
  float* out = (float*)d_out;
  char* ws = (char*)d_ws;

  // ws layout (bytes); total ~84.4 MiB
  unsigned int*   hcnt     = (unsigned int*)(ws + 0);             // 1024 u32 (flags*16)
  float*          row_sums = (float*)(ws + 8192);                 // 2016 f32
  unsigned short* fragWh   = (unsigned short*)(ws + 16384);       // 2 MiB
  unsigned int*   hseq32   = (unsigned int*)(ws + 2113536);       // 2 MiB (64 steps)
  unsigned short* Zx       = (unsigned short*)(ws + 4210688);     // 8.25 MB (bf16)
  float*          enc_proj = (float*)(ws + 12468224);             // 4 MiB
  unsigned short* Afc      = (unsigned short*)(ws + 16662528);    // 4 MiB (2048x1024)
  unsigned short* encT     = (unsigned short*)(ws + 20856832);    // 2 MiB (bf16)
  unsigned short* WfcT     = (unsigned short*)(ws + 22953984);    // 62.5 MiB

  k_zero   <<<dim3(8),          dim3(256), 0, stream>>>(hcnt, row_sums);
  k_fragWh <<<dim3(512),        dim3(256), 0, stream>>>(W_h, fragWh);
  k_zx     <<<dim3(63, 8),      dim3(256), 0, stream>>>(target, emb, W_x, b_lstm, Zx);
  k_encproj<<<dim3(128, 2),     dim3(256), 0, stream>>>(enc_out, Wa, enc_proj);
  k_encT   <<<dim3(32, 8),      dim3(256), 0, stream>>>(enc_out, encT);
  k_wfcT   <<<dim3(1000, 32),   dim3(256), 0, stream>>>(W_fc, WfcT);
  k_rec    <<<dim3(64),         dim3(256), 0, stream>>>(enc_h0, enc_c0,
                                                        enc_proj, Zx, fragWh, encT,
                                                        hseq32, Afc, hcnt);
  k_fc     <<<dim3(250, 16),    dim3(256), 0, stream>>>(Afc, WfcT, b_fc, out, row_sums);
  k_lsm    <<<dim3(63000),      dim3(256), 0, stream>>>(out, row_sums, 16128000);
}